// Round 6
// baseline (130.289 us; speedup 1.0000x reference)
//
#include <hip/hip_runtime.h>
#include <math.h>

constexpr int BS = 32, NV = 321, PL = 12, DM = 128;
constexpr int KT = 32;  // int(64*0.5) patches masked by time criterion
constexpr int KF = 25;  // int(64*0.4) patches masked by freq criterion
constexpr int VB = 4;       // variables per block
constexpr int NCHUNK = 81;  // 80 full chunks + 1 tail chunk (nv=1)
constexpr int SST = 72;     // score row stride: rows land on banks {0,8,16,24}

// ---------------------------------------------------------------------------
// prep: M = W_in @ W_out (12x12), c = b_in @ W_out (12),
//       S_t = tt*colsum(W_out), S_f = ft*colsum(W_out), copy of b_out.
// prep floats: [0,144) M [i][l], [144,156) c, [156,168) S_t, [168,180) S_f,
//              [180,192) b_out
// ---------------------------------------------------------------------------
__global__ void prep_kernel(const float* __restrict__ W_in,
                            const float* __restrict__ b_in,
                            const float* __restrict__ W_out,
                            const float* __restrict__ b_out,
                            const float* __restrict__ tt,
                            const float* __restrict__ ft,
                            float* __restrict__ prep) {
  int t = threadIdx.x;
  if (t < 144) {
    int i = t / 12, l = t % 12;
    const float4* Wi = (const float4*)(W_in + i * DM);
    float s = 0.f;
#pragma unroll 8
    for (int d4 = 0; d4 < 32; ++d4) {
      float4 a = Wi[d4];
      const float* wo = W_out + d4 * 48 + l;
      s += a.x * wo[0] + a.y * wo[12] + a.z * wo[24] + a.w * wo[36];
    }
    prep[t] = s;
  } else if (t < 168) {
    int l = (t - 144) % 12;
    float cs = 0.f, cb = 0.f;
#pragma unroll 8
    for (int d = 0; d < DM; ++d) {
      float w = W_out[d * 12 + l];
      cs += w;
      cb += b_in[d] * w;
    }
    if (t < 156) {
      prep[144 + l] = cb;
      prep[156 + l] = tt[0] * cs;
    } else {
      prep[168 + l] = ft[0] * cs;
    }
  } else if (t < 180) {
    prep[180 + (t - 168)] = b_out[t - 168];
  }
}

// ---------------------------------------------------------------------------
// fused: one block per (b, 4-var chunk); thread <-> one patch (p=t>>2, vv=t&3).
// x in registers end-to-end. Ranking = branch-free per-thread COUNTING over
// the group's 64 scores (broadcast ds_read_b128, conflict-free): no ballots,
// no SALU serial chains, one barrier, no mask exchange. Decode constants come
// from the uniform `prep` pointer -> scalar s_load + v_fma(sgpr), zero LDS.
// ---------------------------------------------------------------------------
__global__ __launch_bounds__(256) void fused_kernel(
    const float* __restrict__ x, const float* __restrict__ prep,
    float* __restrict__ out) {
  __shared__ float scv[VB * SST];
  __shared__ float sfs[VB * SST];

  const int t = threadIdx.x;
  const int chunk = blockIdx.x;  // 0..80
  const int b = blockIdx.y;      // 0..31
  const int v0 = chunk * VB;
  const bool full = (chunk < 80);
  const int p = t >> 2;   // 0..63
  const int vv = t & 3;   // 0..3
  const bool valid = full || (vv == 0);

  // ---- load this thread's patch (lanes sweep vv -> 192B contiguous runs) ----
  float xr[12];
  if (valid) {
    const float4* src =
        (const float4*)(x + (((size_t)(b * 64 + p) * NV) + v0 + vv) * PL);
    float4 a = src[0], bb = src[1], c = src[2];
    xr[0] = a.x;  xr[1] = a.y;  xr[2] = a.z;  xr[3] = a.w;
    xr[4] = bb.x; xr[5] = bb.y; xr[6] = bb.z; xr[7] = bb.w;
    xr[8] = c.x;  xr[9] = c.y;  xr[10] = c.z; xr[11] = c.w;
  }

  // ---- scores from registers; 2 floats/patch to LDS ----
  float cv = 0.f, fs = 0.f;
  const float H = 0.86602540378443864676f;  // sqrt(3)/2
  if (valid) {
    const float* xv = xr;
    // coefficient of variation: std(ddof=1)/(mean+1e-6)
    float s = 0.f;
#pragma unroll
    for (int i = 0; i < 12; ++i) s += xv[i];
    const float m = s * (1.0f / 12.0f);
    float ss = 0.f;
#pragma unroll
    for (int i = 0; i < 12; ++i) {
      float d = xv[i] - m;
      ss += d * d;
    }
    cv = sqrtf(ss * (1.0f / 11.0f)) / (m + 1e-6f);

    // mean |rfft12| over 7 bins, even/odd folded exact 30-degree DFT
    const float e1 = xv[1] + xv[11], e2 = xv[2] + xv[10], e3 = xv[3] + xv[9],
                e4 = xv[4] + xv[8], e5 = xv[5] + xv[7];
    const float o1 = xv[1] - xv[11], o2 = xv[2] - xv[10], o3 = xv[3] - xv[9],
                o4 = xv[4] - xv[8], o5 = xv[5] - xv[7];
    float mag = fabsf(xv[0] + xv[6] + e1 + e2 + e3 + e4 + e5);  // k=0
    float re = xv[0] - xv[6] + H * (e1 - e5) + 0.5f * (e2 - e4);
    float im = 0.5f * (o1 + o5) + H * (o2 + o4) + o3;
    mag += sqrtf(re * re + im * im);  // k=1
    re = xv[0] + xv[6] + 0.5f * (e1 + e5) - 0.5f * (e2 + e4) - e3;
    im = H * (o1 + o2 - o4 - o5);
    mag += sqrtf(re * re + im * im);  // k=2
    re = xv[0] - xv[6] - e2 + e4;
    im = o1 - o3 + o5;
    mag += sqrtf(re * re + im * im);  // k=3
    re = xv[0] + xv[6] - 0.5f * (e1 + e2 + e4 + e5) + e3;
    im = H * (o1 - o2 + o4 - o5);
    mag += sqrtf(re * re + im * im);  // k=4
    re = xv[0] - xv[6] + H * (e5 - e1) + 0.5f * (e2 - e4);
    im = 0.5f * (o1 + o5) - H * (o2 + o4) + o3;
    mag += sqrtf(re * re + im * im);  // k=5
    re = xv[0] + xv[6] - e1 + e2 - e3 + e4 - e5;
    mag += fabsf(re);  // k=6
    fs = mag * (1.0f / 7.0f);

    scv[vv * SST + p] = cv;
    sfs[vv * SST + p] = fs;
  }
  __syncthreads();

  // ---- branch-free counting rank (stable, matches lax.top_k ties) ----
  // position (descending for cv / ascending for fs) = gt + eq_with_smaller_idx
  int gt_t = 0, eqb_t = 0, gt_f = 0, eqb_f = 0;
  if (valid) {
    const float4* rc = (const float4*)(scv + vv * SST);
    const float4* rf = (const float4*)(sfs + vv * SST);
#pragma unroll
    for (int q4 = 0; q4 < 16; ++q4) {  // broadcast b128, banks spread by SST
      const float4 c4 = rc[q4];
      const float4 f4 = rf[q4];
      const int q = q4 * 4;
      gt_t += (c4.x > cv) + (c4.y > cv) + (c4.z > cv) + (c4.w > cv);
      gt_f += (f4.x < fs) + (f4.y < fs) + (f4.z < fs) + (f4.w < fs);
      eqb_t += ((c4.x == cv) & (q + 0 < p)) + ((c4.y == cv) & (q + 1 < p)) +
               ((c4.z == cv) & (q + 2 < p)) + ((c4.w == cv) & (q + 3 < p));
      eqb_f += ((f4.x == fs) & (q + 0 < p)) + ((f4.y == fs) & (q + 1 < p)) +
               ((f4.z == fs) & (q + 2 < p)) + ((f4.w == fs) & (q + 3 < p));
    }
  }
  const bool kt = (gt_t + eqb_t) >= KT;  // keep iff NOT in top-KT largest cv
  const bool kf = (gt_f + eqb_f) >= KF;  // keep iff NOT in KF smallest fs

  // ---- decode: E = x.M + c via uniform scalar loads of prep ----
  float E[12];
#pragma unroll
  for (int l = 0; l < 12; ++l) E[l] = prep[144 + l];
#pragma unroll
  for (int i = 0; i < 12; ++i) {
    const float a = xr[i];
#pragma unroll
    for (int l = 0; l < 12; ++l) E[l] += a * prep[i * 12 + l];
  }
  if (valid) {
    float o[12];
#pragma unroll
    for (int l = 0; l < 12; ++l) {
      const float at = kt ? E[l] : prep[156 + l];
      const float af = kf ? E[l] : prep[168 + l];
      o[l] = 0.5f * (at + af) + prep[180 + l];
    }
    float* op = out + (((size_t)(b * 64 + p) * NV) + v0 + vv) * PL;
    ((float4*)op)[0] = make_float4(o[0], o[1], o[2], o[3]);
    ((float4*)op)[1] = make_float4(o[4], o[5], o[6], o[7]);
    ((float4*)op)[2] = make_float4(o[8], o[9], o[10], o[11]);
  }
}

extern "C" void kernel_launch(void* const* d_in, const int* in_sizes, int n_in,
                              void* d_out, int out_size, void* d_ws,
                              size_t ws_size, hipStream_t stream) {
  const float* x = (const float*)d_in[0];
  const float* W_in = (const float*)d_in[1];
  const float* b_in = (const float*)d_in[2];
  const float* W_out = (const float*)d_in[3];
  const float* b_out = (const float*)d_in[4];
  const float* tt = (const float*)d_in[5];
  const float* ft = (const float*)d_in[6];
  float* out = (float*)d_out;
  float* prep = (float*)d_ws;  // 192 floats

  hipLaunchKernelGGL(prep_kernel, dim3(1), dim3(192), 0, stream, W_in, b_in,
                     W_out, b_out, tt, ft, prep);
  hipLaunchKernelGGL(fused_kernel, dim3(NCHUNK, BS), dim3(256), 0, stream, x,
                     prep, out);
}

// Round 7
// 122.607 us; speedup vs baseline: 1.0626x; 1.0626x over previous
//
#include <hip/hip_runtime.h>
#include <math.h>

constexpr int BS = 32, NV = 321, PL = 12, DM = 128;
constexpr int KT = 32;  // int(64*0.5) patches masked by time criterion
constexpr int KF = 25;  // int(64*0.4) patches masked by freq criterion
constexpr int VB = 4;       // variables per block
constexpr int NCHUNK = 81;  // 80 full chunks + 1 tail chunk (nv=1)
constexpr int SST = 72;     // score row stride: rows start at banks {0,8,16,24}

// map float -> uint such that uint order == float order (total, -0 < +0)
__device__ __forceinline__ unsigned ord(float f) {
  unsigned u = __float_as_uint(f);
  return ((int)u < 0) ? ~u : (u | 0x80000000u);
}

// ---------------------------------------------------------------------------
// Single fused kernel. One block per (b, 4-var chunk); thread <-> one patch
// (p = t>>2, vv = t&3; lanes sweep vv -> 192B contiguous global runs).
//  phase 0: issue x loads; meanwhile threads 0..179 compute the collapsed
//           decode constants (M = W_in@W_out etc.) from L2-hot W into LDS.
//  phase 1: per-patch scores from registers -> 2 floats/patch to LDS.
//  phase 2: wave wv ranks group vv=wv with a dual 32-step BALLOT radix
//           (1 v_cmp evaluates all 64 candidates; ~70 VALU inst total) and
//           publishes two u64 keep-masks per group.
//  phase 3: decode E = x.M + c with M read as uniform-address b128 LDS
//           broadcasts; masked average; coalesced float4 stores.
// ---------------------------------------------------------------------------
__global__ __launch_bounds__(256) void fused_kernel(
    const float* __restrict__ x, const float* __restrict__ W_in,
    const float* __restrict__ b_in, const float* __restrict__ W_out,
    const float* __restrict__ b_out, const float* __restrict__ tt,
    const float* __restrict__ ft, float* __restrict__ out) {
  __shared__ float scv[VB * SST];
  __shared__ float sfs[VB * SST];
  __shared__ __align__(16) float spp[192];  // M(144) c(12) St(12) Sf(12) b(12)
  __shared__ unsigned long long smT[VB], smF[VB];

  const int t = threadIdx.x;
  const int chunk = blockIdx.x;  // 0..80
  const int b = blockIdx.y;      // 0..31
  const int v0 = chunk * VB;
  const bool full = (chunk < 80);
  const int p = t >> 2;  // 0..63
  const int vv = t & 3;  // 0..3
  const bool valid = full || (vv == 0);

  // ---- phase 0a: this thread's patch (guarded: tail chunk has only vv=0) ----
  float xr[12];
  if (valid) {
    const float4* src =
        (const float4*)(x + (((size_t)(b * 64 + p) * NV) + v0 + vv) * PL);
    float4 a = src[0], bb = src[1], c = src[2];
    xr[0] = a.x;  xr[1] = a.y;  xr[2] = a.z;  xr[3] = a.w;
    xr[4] = bb.x; xr[5] = bb.y; xr[6] = bb.z; xr[7] = bb.w;
    xr[8] = c.x;  xr[9] = c.y;  xr[10] = c.z; xr[11] = c.w;
  }

  // ---- phase 0b: in-block prep from L2-hot W (overlaps x-load latency) ----
  if (t < 144) {
    const int i = t / 12, l = t - (t / 12) * 12;
    const float4* Wi = (const float4*)(W_in + i * DM);
    float s = 0.f;
#pragma unroll 8
    for (int d4 = 0; d4 < 32; ++d4) {
      float4 a = Wi[d4];
      const float* wo = W_out + d4 * 48 + l;
      s += a.x * wo[0] + a.y * wo[12] + a.z * wo[24] + a.w * wo[36];
    }
    spp[t] = s;
  } else if (t < 168) {
    const int l = (t - 144) % 12;
    float cs = 0.f, cb = 0.f;
#pragma unroll 8
    for (int d = 0; d < DM; ++d) {
      float w = W_out[d * 12 + l];
      cs += w;
      cb += b_in[d] * w;
    }
    if (t < 156) {
      spp[144 + l] = cb;
      spp[156 + l] = tt[0] * cs;
    } else {
      spp[168 + l] = ft[0] * cs;
    }
  } else if (t < 180) {
    spp[180 + (t - 168)] = b_out[t - 168];
  }

  // ---- phase 1: scores from registers; 2 floats/patch to LDS ----
  const float H = 0.86602540378443864676f;  // sqrt(3)/2
  if (valid) {
    const float* xv = xr;
    // coefficient of variation: std(ddof=1)/(mean+1e-6)
    float s = 0.f;
#pragma unroll
    for (int i = 0; i < 12; ++i) s += xv[i];
    const float m = s * (1.0f / 12.0f);
    float ss = 0.f;
#pragma unroll
    for (int i = 0; i < 12; ++i) {
      float d = xv[i] - m;
      ss += d * d;
    }
    const float cv = sqrtf(ss * (1.0f / 11.0f)) / (m + 1e-6f);

    // mean |rfft12| over 7 bins, even/odd folded exact 30-degree DFT
    const float e1 = xv[1] + xv[11], e2 = xv[2] + xv[10], e3 = xv[3] + xv[9],
                e4 = xv[4] + xv[8], e5 = xv[5] + xv[7];
    const float o1 = xv[1] - xv[11], o2 = xv[2] - xv[10], o3 = xv[3] - xv[9],
                o4 = xv[4] - xv[8], o5 = xv[5] - xv[7];
    float mag = fabsf(xv[0] + xv[6] + e1 + e2 + e3 + e4 + e5);  // k=0
    float re = xv[0] - xv[6] + H * (e1 - e5) + 0.5f * (e2 - e4);
    float im = 0.5f * (o1 + o5) + H * (o2 + o4) + o3;
    mag += sqrtf(re * re + im * im);  // k=1
    re = xv[0] + xv[6] + 0.5f * (e1 + e5) - 0.5f * (e2 + e4) - e3;
    im = H * (o1 + o2 - o4 - o5);
    mag += sqrtf(re * re + im * im);  // k=2
    re = xv[0] - xv[6] - e2 + e4;
    im = o1 - o3 + o5;
    mag += sqrtf(re * re + im * im);  // k=3
    re = xv[0] + xv[6] - 0.5f * (e1 + e2 + e4 + e5) + e3;
    im = H * (o1 - o2 + o4 - o5);
    mag += sqrtf(re * re + im * im);  // k=4
    re = xv[0] - xv[6] + H * (e5 - e1) + 0.5f * (e2 - e4);
    im = 0.5f * (o1 + o5) - H * (o2 + o4) + o3;
    mag += sqrtf(re * re + im * im);  // k=5
    re = xv[0] + xv[6] - e1 + e2 - e3 + e4 - e5;
    mag += fabsf(re);  // k=6
    const float fs = mag * (1.0f / 7.0f);

    scv[vv * SST + p] = cv;  // banks (vv*8+p)%32: exact 2-way -> free
    sfs[vv * SST + p] = fs;
  }
  __syncthreads();

  // ---- phase 2: dual ballot radix top-k; wave wv ranks group vv=wv ----
  const int wv = t >> 6, lane = t & 63;
  if (full || wv == 0) {  // wave-uniform
    const unsigned ut = ord(scv[wv * SST + lane]);   // rank KT LARGEST cv
    const unsigned uf = ~ord(sfs[wv * SST + lane]);  // rank KF SMALLEST fs
    unsigned tht = 0, thf = 0;
#pragma unroll
    for (int bit = 31; bit >= 0; --bit) {
      const unsigned ct = tht | (1u << bit);
      const unsigned cf = thf | (1u << bit);
      const unsigned long long bt = __ballot(ut >= ct);
      const unsigned long long bf = __ballot(uf >= cf);
      if (__popcll(bt) >= KT) tht = ct;  // tht -> K-th largest key
      if (__popcll(bf) >= KF) thf = cf;
    }
    const unsigned long long pre = (1ull << lane) - 1ull;
    const int gt_t = __popcll(__ballot(ut > tht));
    const int rt = __popcll(__ballot(ut == tht) & pre);
    const bool masked_t = (ut > tht) || ((ut == tht) && (rt < KT - gt_t));
    const int gt_f = __popcll(__ballot(uf > thf));
    const int rf = __popcll(__ballot(uf == thf) & pre);
    const bool masked_f = (uf > thf) || ((uf == thf) && (rf < KF - gt_f));
    const unsigned long long bkt = __ballot(!masked_t);
    const unsigned long long bkf = __ballot(!masked_f);
    if (lane == 0) {
      smT[wv] = bkt;
      smF[wv] = bkf;
    }
  }
  __syncthreads();

  // ---- phase 3: decode from registers; M via uniform b128 LDS broadcasts ----
  const bool kt = (smT[vv] >> p) & 1ull;
  const bool kf = (smF[vv] >> p) & 1ull;
  float E[12];
#pragma unroll
  for (int l = 0; l < 12; ++l) E[l] = spp[144 + l];
  const float4* M4 = (const float4*)spp;
#pragma unroll
  for (int i = 0; i < 12; ++i) {
    const float4 m0 = M4[i * 3], m1 = M4[i * 3 + 1], m2 = M4[i * 3 + 2];
    const float a = xr[i];
    E[0] += a * m0.x;  E[1] += a * m0.y;  E[2] += a * m0.z;  E[3] += a * m0.w;
    E[4] += a * m1.x;  E[5] += a * m1.y;  E[6] += a * m1.z;  E[7] += a * m1.w;
    E[8] += a * m2.x;  E[9] += a * m2.y;  E[10] += a * m2.z; E[11] += a * m2.w;
  }
  if (valid) {
    float o[12];
#pragma unroll
    for (int l = 0; l < 12; ++l) {
      const float at = kt ? E[l] : spp[156 + l];
      const float af = kf ? E[l] : spp[168 + l];
      o[l] = 0.5f * (at + af) + spp[180 + l];
    }
    float* op = out + (((size_t)(b * 64 + p) * NV) + v0 + vv) * PL;
    ((float4*)op)[0] = make_float4(o[0], o[1], o[2], o[3]);
    ((float4*)op)[1] = make_float4(o[4], o[5], o[6], o[7]);
    ((float4*)op)[2] = make_float4(o[8], o[9], o[10], o[11]);
  }
}

extern "C" void kernel_launch(void* const* d_in, const int* in_sizes, int n_in,
                              void* d_out, int out_size, void* d_ws,
                              size_t ws_size, hipStream_t stream) {
  const float* x = (const float*)d_in[0];
  const float* W_in = (const float*)d_in[1];
  const float* b_in = (const float*)d_in[2];
  const float* W_out = (const float*)d_in[3];
  const float* b_out = (const float*)d_in[4];
  const float* tt = (const float*)d_in[5];
  const float* ft = (const float*)d_in[6];
  float* out = (float*)d_out;

  hipLaunchKernelGGL(fused_kernel, dim3(NCHUNK, BS), dim3(256), 0, stream, x,
                     W_in, b_in, W_out, b_out, tt, ft, out);
}